// Round 1
// baseline (141.356 us; speedup 1.0000x reference)
//
#include <hip/hip_runtime.h>

// BEVTrans: out[b, c*5+h, d, w] = bilinear_sample(X[b,c], ix(b,w,h,d), iy(b,w,h,d))
//   ix = 319*(c00*wx + c01*hy + c02*dz)/dz,  iy = 95*(c10*wx + c11*hy + c12*dz)/dz
//   wx = -9.9 + 0.2*w (100), hy = -3 + h (5), dz = 0.1 + 0.2*d (100)
// X: [4,256,96,320] f32, calib: [4,3,3] f32, out: [4,1280,100,100] f32 (51.2M elems)

#define W_IN   320
#define H_IN   96
#define SLICE  (H_IN * W_IN)   // 30720 floats per (b,c)

__global__ __launch_bounds__(256) void bev_kernel(const float* __restrict__ X,
                                                  const float* __restrict__ calib,
                                                  float* __restrict__ out) {
    const int bc = blockIdx.x;          // 0..1023 = b*256 + c
    const int b  = bc >> 8;
    const int c  = bc & 255;

    const float* __restrict__ Xs = X + (size_t)bc * SLICE;
    const float* cb = calib + b * 9;
    const float c00 = cb[0], c01 = cb[1], c02 = cb[2];
    const float c10 = cb[3], c11 = cb[4], c12 = cb[5];
    // calib row 2 is exactly [0,0,1] (reference zeroes its noise) -> z = dz

    float* __restrict__ outb = out + ((size_t)b * 1280 + (size_t)c * 5) * 10000;

    // 50,000 items per block, ordered item = d*500 + h*100 + w (w innermost
    // so lane-adjacent writes are contiguous and gathers are x-adjacent).
    for (int item = threadIdx.x; item < 50000; item += 256) {
        int d = item / 500;
        int r = item - d * 500;
        int h = r / 100;
        int w = r - h * 100;

        float wxv = -9.9f + 0.2f * (float)w;
        float hyv = -3.0f + (float)h;
        float dzv =  0.1f + 0.2f * (float)d;
        float inv = 1.0f / dzv;

        float ix = 319.0f * inv * (c00 * wxv + c01 * hyv + c02 * dzv);
        float iy =  95.0f * inv * (c10 * wxv + c11 * hyv + c12 * dzv);

        float fx0 = floorf(ix);
        float fy0 = floorf(iy);
        int ix0 = (int)fx0;
        int iy0 = (int)fy0;

        float res = 0.0f;
        // all four corners invalid iff ix0 < -1 || ix0 > 319 || iy0 < -1 || iy0 > 95
        if (!(ix0 < -1 || ix0 > 319 || iy0 < -1 || iy0 > 95)) {
            float ax = ix - fx0;              // frac in [0,1)
            float ay = iy - fy0;
            float wx0 = (ix0 >= 0)   ? (1.0f - ax) : 0.0f;
            float wx1 = (ix0 <= 318) ? ax          : 0.0f;
            float wy0 = (iy0 >= 0)   ? (1.0f - ay) : 0.0f;
            float wy1 = (iy0 <= 94)  ? ay          : 0.0f;
            int x0 = max(ix0, 0);
            int x1 = min(ix0 + 1, W_IN - 1);
            int y0 = max(iy0, 0);
            int y1 = min(iy0 + 1, H_IN - 1);
            const float* row0 = Xs + y0 * W_IN;
            const float* row1 = Xs + y1 * W_IN;
            res = wy0 * (wx0 * row0[x0] + wx1 * row0[x1])
                + wy1 * (wx0 * row1[x0] + wx1 * row1[x1]);
        }
        outb[(size_t)h * 10000 + (size_t)d * 100 + (size_t)w] = res;
    }
}

extern "C" void kernel_launch(void* const* d_in, const int* in_sizes, int n_in,
                              void* d_out, int out_size, void* d_ws, size_t ws_size,
                              hipStream_t stream) {
    const float* X     = (const float*)d_in[0];   // [4,256,96,320]
    const float* calib = (const float*)d_in[1];   // [4,3,3]
    float* out = (float*)d_out;                   // [4,1280,100,100]

    bev_kernel<<<dim3(1024), dim3(256), 0, stream>>>(X, calib, out);
}

// Round 3
// 109.657 us; speedup vs baseline: 1.2891x; 1.2891x over previous
//
#include <hip/hip_runtime.h>

// BEVTrans: out[b, c*5+h, d, w] = bilinear_sample(X[b,c], ix(b,w,h,d), iy(b,w,h,d))
//   ix = 319*(c00*wx + c01*hy + c02*dz)/dz,  iy = 95*(c10*wx + c11*hy + c12*dz)/dz
//   (calib row 2 is exactly [0,0,1] in the reference -> z = dz)
// X: [4,256,96,320] f32, calib: [4,3,3] f32, out: [4,1280,100,100] f32
//
// R1 restructure: coords computed ONCE per geometric position, reused across a
// 32-channel group (grid.y = b*8+cg). Each thread owns 4 consecutive w -> one
// float4 store per channel. Border clamps folded into shifted weights so all 4
// bilinear corners read from ONE base offset with compile-time imm offsets
// (+0,+4,+1280,+1284 bytes).
// R2: ext_vector_type for the nontemporal store (HIP float4 class rejected).

#define W_IN  320
#define H_IN  96
#define SLICE (H_IN * W_IN)     // 30720 floats per (b,c)
#define CG    32                // channels per block
#define NT4   12500             // 50000 positions / 4 per batch

typedef float f32x4 __attribute__((ext_vector_type(4)));

__global__ __launch_bounds__(256) void bev_kernel(const float* __restrict__ X,
                                                  const float* __restrict__ calib,
                                                  float* __restrict__ out) {
    const int bcg = blockIdx.y;            // b*8 + channel_group
    const int b   = bcg >> 3;
    const int c0  = (bcg & 7) * CG;
    const int t   = blockIdx.x * 256 + threadIdx.x;   // pos4 index within batch
    if (t >= NT4) return;

    const int item = t * 4;                // 4 consecutive items share (d,h); 100%4==0
    const int d = item / 500;
    const int r = item - d * 500;
    const int h = r / 100;
    const int w0 = r - h * 100;

    const float* cb = calib + b * 9;
    const float c00 = cb[0], c01 = cb[1], c02 = cb[2];
    const float c10 = cb[3], c11 = cb[4], c12 = cb[5];

    const float hyv = -3.0f + (float)h;
    const float dzv = 0.1f + 0.2f * (float)d;
    const float inv = 1.0f / dzv;

    int   off[4];
    float W00[4], W01[4], W10[4], W11[4];
    float wsum = 0.0f;
    #pragma unroll
    for (int j = 0; j < 4; ++j) {
        const float wxv = -9.9f + 0.2f * (float)(w0 + j);
        const float ix = 319.0f * inv * (c00 * wxv + c01 * hyv + c02 * dzv);
        const float iy =  95.0f * inv * (c10 * wxv + c11 * hyv + c12 * dzv);
        const float fx0 = floorf(ix), fy0 = floorf(iy);
        const int ix0 = (int)fx0, iy0 = (int)fy0;
        const float ax = ix - fx0, ay = iy - fy0;

        // shifted-weight formulation: weights apply to (xc, xc+1), xc=clamp(ix0,0,318)
        float a0, a1, b0, b1;
        if (ix0 >= 0 && ix0 <= 318)      { a0 = 1.0f - ax; a1 = ax; }
        else if (ix0 == -1)              { a0 = ax;        a1 = 0.0f; }
        else if (ix0 == 319)             { a0 = 0.0f;      a1 = 1.0f - ax; }
        else                             { a0 = 0.0f;      a1 = 0.0f; }
        if (iy0 >= 0 && iy0 <= 94)       { b0 = 1.0f - ay; b1 = ay; }
        else if (iy0 == -1)              { b0 = ay;        b1 = 0.0f; }
        else if (iy0 == 95)              { b0 = 0.0f;      b1 = 1.0f - ay; }
        else                             { b0 = 0.0f;      b1 = 0.0f; }

        const int xc = min(max(ix0, 0), 318);
        const int yc = min(max(iy0, 0), 94);
        off[j] = yc * W_IN + xc;
        W00[j] = a0 * b0;  W01[j] = a1 * b0;
        W10[j] = a0 * b1;  W11[j] = a1 * b1;
        wsum += W00[j] + W01[j] + W10[j] + W11[j];
    }

    const float* Xc = X + ((size_t)b * 256 + (size_t)c0) * SLICE;
    float* oc = out + ((size_t)b * 1280 + (size_t)c0 * 5 + (size_t)h) * 10000
                    + d * 100 + w0;

    if (wsum > 0.0f) {
        #pragma unroll 2
        for (int cc = 0; cc < CG; ++cc) {
            f32x4 res;
            #pragma unroll
            for (int j = 0; j < 4; ++j) {
                const float* p = Xc + off[j];
                float v = W00[j] * p[0];
                v = fmaf(W01[j], p[1],   v);
                v = fmaf(W10[j], p[320], v);
                v = fmaf(W11[j], p[321], v);
                res[j] = v;
            }
            __builtin_nontemporal_store(res, (f32x4*)oc);
            Xc += SLICE;
            oc += 50000;
        }
    } else {
        const f32x4 z = {0.0f, 0.0f, 0.0f, 0.0f};
        #pragma unroll 4
        for (int cc = 0; cc < CG; ++cc) {
            __builtin_nontemporal_store(z, (f32x4*)oc);
            oc += 50000;
        }
    }
}

extern "C" void kernel_launch(void* const* d_in, const int* in_sizes, int n_in,
                              void* d_out, int out_size, void* d_ws, size_t ws_size,
                              hipStream_t stream) {
    const float* X     = (const float*)d_in[0];   // [4,256,96,320]
    const float* calib = (const float*)d_in[1];   // [4,3,3]
    float* out = (float*)d_out;                   // [4,1280,100,100]

    dim3 grid((NT4 + 255) / 256, 32);             // 49 x (4 batches * 8 channel-groups)
    bev_kernel<<<grid, dim3(256), 0, stream>>>(X, calib, out);
}

// Round 4
// 91.075 us; speedup vs baseline: 1.5521x; 1.2040x over previous
//
#include <hip/hip_runtime.h>

// BEVTrans: out[b, c*5+h, d, w] = bilinear_sample(X[b,c], ix(b,w,h,d), iy(b,w,h,d))
//   ix = 319*(c00*wx + c01*hy + c02*dz)/dz,  iy = 95*(c10*wx + c11*hy + c12*dz)/dz
//   (calib row 2 is exactly [0,0,1] in the reference -> z = dz)
// X: [4,256,96,320] f32, calib: [4,3,3] f32, out: [4,1280,100,100] f32
//
// R3: one item per thread (lanes span consecutive w -> lane ix-spacing 1.9/dz px,
// 4x tighter than R2 -> far fewer cache lines per wave gather). CG=16 channels
// per thread, coords computed once and reused. Shifted-weight border handling:
// all 4 corners read from one clamped base with imm offsets +0,+4,+1280,+1284.

#define W_IN  320
#define H_IN  96
#define SLICE (H_IN * W_IN)     // 30720 floats per (b,c)
#define CG    16                // channels per thread
#define NITEMS 50000

__global__ __launch_bounds__(256) void bev_kernel(const float* __restrict__ X,
                                                  const float* __restrict__ calib,
                                                  float* __restrict__ out) {
    const int bcg = blockIdx.y;            // b*16 + channel_group
    const int b   = bcg >> 4;
    const int c0  = (bcg & 15) * CG;
    const int t   = blockIdx.x * 256 + threadIdx.x;
    if (t >= NITEMS) return;

    const int d = t / 500;
    const int r = t - d * 500;
    const int h = r / 100;
    const int w = r - h * 100;

    const float* cb = calib + b * 9;
    const float c00 = cb[0], c01 = cb[1], c02 = cb[2];
    const float c10 = cb[3], c11 = cb[4], c12 = cb[5];

    const float wxv = -9.9f + 0.2f * (float)w;
    const float hyv = -3.0f + (float)h;
    const float dzv = 0.1f + 0.2f * (float)d;
    const float inv = 1.0f / dzv;

    const float ix = 319.0f * inv * (c00 * wxv + c01 * hyv + c02 * dzv);
    const float iy =  95.0f * inv * (c10 * wxv + c11 * hyv + c12 * dzv);
    const float fx0 = floorf(ix), fy0 = floorf(iy);
    const int ix0 = (int)fx0, iy0 = (int)fy0;
    const float ax = ix - fx0, ay = iy - fy0;

    // shifted-weight formulation: weights apply to (xc, xc+1), xc=clamp(ix0,0,318)
    float a0, a1, b0, b1;
    if (ix0 >= 0 && ix0 <= 318)      { a0 = 1.0f - ax; a1 = ax; }
    else if (ix0 == -1)              { a0 = ax;        a1 = 0.0f; }
    else if (ix0 == 319)             { a0 = 0.0f;      a1 = 1.0f - ax; }
    else                             { a0 = 0.0f;      a1 = 0.0f; }
    if (iy0 >= 0 && iy0 <= 94)       { b0 = 1.0f - ay; b1 = ay; }
    else if (iy0 == -1)              { b0 = ay;        b1 = 0.0f; }
    else if (iy0 == 95)              { b0 = 0.0f;      b1 = 1.0f - ay; }
    else                             { b0 = 0.0f;      b1 = 0.0f; }

    const int xc = min(max(ix0, 0), 318);
    const int yc = min(max(iy0, 0), 94);
    const int off = yc * W_IN + xc;
    const float W00 = a0 * b0, W01 = a1 * b0, W10 = a0 * b1, W11 = a1 * b1;
    const float wsum = W00 + W01 + W10 + W11;

    const float* Xc = X + ((size_t)b * 256 + (size_t)c0) * SLICE + off;
    float* oc = out + ((size_t)b * 1280 + (size_t)c0 * 5 + (size_t)h) * 10000
                    + d * 100 + w;

    if (wsum > 0.0f) {
        #pragma unroll 4
        for (int cc = 0; cc < CG; ++cc) {
            float v = W00 * Xc[0];
            v = fmaf(W01, Xc[1],   v);
            v = fmaf(W10, Xc[320], v);
            v = fmaf(W11, Xc[321], v);
            __builtin_nontemporal_store(v, oc);
            Xc += SLICE;
            oc += 50000;
        }
    } else {
        #pragma unroll 8
        for (int cc = 0; cc < CG; ++cc) {
            __builtin_nontemporal_store(0.0f, oc);
            oc += 50000;
        }
    }
}

extern "C" void kernel_launch(void* const* d_in, const int* in_sizes, int n_in,
                              void* d_out, int out_size, void* d_ws, size_t ws_size,
                              hipStream_t stream) {
    const float* X     = (const float*)d_in[0];   // [4,256,96,320]
    const float* calib = (const float*)d_in[1];   // [4,3,3]
    float* out = (float*)d_out;                   // [4,1280,100,100]

    dim3 grid((NITEMS + 255) / 256, 64);          // 196 x (4 batches * 16 groups)
    bev_kernel<<<grid, dim3(256), 0, stream>>>(X, calib, out);
}

// Round 5
// 82.301 us; speedup vs baseline: 1.7176x; 1.1066x over previous
//
#include <hip/hip_runtime.h>

// BEVTrans: out[b, c*5+h, d, w] = bilinear_sample(X[b,c], ix(b,w,h,d), iy(b,w,h,d))
//   ix = 319*(c00*wx + c01*hy + c02*dz)/dz,  iy = 95*(c10*wx + c11*hy + c12*dz)/dz
//   (calib row 2 is exactly [0,0,1] in the reference -> z = dz)
// X: [4,256,96,320] f32, calib: [4,3,3] f32, out: [4,1280,100,100] f32
//
// R4: latency-bound fix — full-depth MLP. Each thread loads ALL 64 corner
// values (16 channels x 4 corners) into registers before computing, so the
// wave keeps 64 loads outstanding instead of 16 (R3's unroll-4 window).
// Lanes still span consecutive w (tight gather footprint), stores coalesced.

#define W_IN  320
#define H_IN  96
#define SLICE (H_IN * W_IN)     // 30720 floats per (b,c)
#define CG    16                // channels per thread
#define NITEMS 50000

__global__ __launch_bounds__(256) void bev_kernel(const float* __restrict__ X,
                                                  const float* __restrict__ calib,
                                                  float* __restrict__ out) {
    const int bcg = blockIdx.y;            // b*16 + channel_group
    const int b   = bcg >> 4;
    const int c0  = (bcg & 15) * CG;
    const int t   = blockIdx.x * 256 + threadIdx.x;
    if (t >= NITEMS) return;

    const int d = t / 500;
    const int r = t - d * 500;
    const int h = r / 100;
    const int w = r - h * 100;

    const float* cb = calib + b * 9;
    const float c00 = cb[0], c01 = cb[1], c02 = cb[2];
    const float c10 = cb[3], c11 = cb[4], c12 = cb[5];

    const float wxv = -9.9f + 0.2f * (float)w;
    const float hyv = -3.0f + (float)h;
    const float dzv = 0.1f + 0.2f * (float)d;
    const float inv = 1.0f / dzv;

    const float ix = 319.0f * inv * (c00 * wxv + c01 * hyv + c02 * dzv);
    const float iy =  95.0f * inv * (c10 * wxv + c11 * hyv + c12 * dzv);
    const float fx0 = floorf(ix), fy0 = floorf(iy);
    const int ix0 = (int)fx0, iy0 = (int)fy0;
    const float ax = ix - fx0, ay = iy - fy0;

    // shifted-weight formulation: weights apply to (xc, xc+1), xc=clamp(ix0,0,318)
    float a0, a1, b0, b1;
    if (ix0 >= 0 && ix0 <= 318)      { a0 = 1.0f - ax; a1 = ax; }
    else if (ix0 == -1)              { a0 = ax;        a1 = 0.0f; }
    else if (ix0 == 319)             { a0 = 0.0f;      a1 = 1.0f - ax; }
    else                             { a0 = 0.0f;      a1 = 0.0f; }
    if (iy0 >= 0 && iy0 <= 94)       { b0 = 1.0f - ay; b1 = ay; }
    else if (iy0 == -1)              { b0 = ay;        b1 = 0.0f; }
    else if (iy0 == 95)              { b0 = 0.0f;      b1 = 1.0f - ay; }
    else                             { b0 = 0.0f;      b1 = 0.0f; }

    const int xc = min(max(ix0, 0), 318);
    const int yc = min(max(iy0, 0), 94);
    const int off = yc * W_IN + xc;
    const float W00 = a0 * b0, W01 = a1 * b0, W10 = a0 * b1, W11 = a1 * b1;
    const float wsum = W00 + W01 + W10 + W11;

    const float* Xc = X + ((size_t)b * 256 + (size_t)c0) * SLICE + off;
    float* oc = out + ((size_t)b * 1280 + (size_t)c0 * 5 + (size_t)h) * 10000
                    + d * 100 + w;

    if (wsum > 0.0f) {
        float v00[CG], v01[CG], v10[CG], v11[CG];
        // phase 1: issue all 64 loads (deep vmcnt pipeline)
        #pragma unroll
        for (int cc = 0; cc < CG; ++cc) {
            const float* p = Xc + (size_t)cc * SLICE;
            v00[cc] = p[0];
            v01[cc] = p[1];
            v10[cc] = p[320];
            v11[cc] = p[321];
        }
        // phase 2: combine + store
        #pragma unroll
        for (int cc = 0; cc < CG; ++cc) {
            float v = W00 * v00[cc];
            v = fmaf(W01, v01[cc], v);
            v = fmaf(W10, v10[cc], v);
            v = fmaf(W11, v11[cc], v);
            __builtin_nontemporal_store(v, oc + (size_t)cc * 50000);
        }
    } else {
        #pragma unroll
        for (int cc = 0; cc < CG; ++cc) {
            __builtin_nontemporal_store(0.0f, oc + (size_t)cc * 50000);
        }
    }
}

extern "C" void kernel_launch(void* const* d_in, const int* in_sizes, int n_in,
                              void* d_out, int out_size, void* d_ws, size_t ws_size,
                              hipStream_t stream) {
    const float* X     = (const float*)d_in[0];   // [4,256,96,320]
    const float* calib = (const float*)d_in[1];   // [4,3,3]
    float* out = (float*)d_out;                   // [4,1280,100,100]

    dim3 grid((NITEMS + 255) / 256, 64);          // 196 x (4 batches * 16 groups)
    bev_kernel<<<grid, dim3(256), 0, stream>>>(X, calib, out);
}